// Round 3
// baseline (357.151 us; speedup 1.0000x reference)
//
#include <hip/hip_runtime.h>
#include <math.h>

#define NN 50000
#define NN4 12500          // NN/4 packed u8 bins (u32 words)
#define NE 800000
#define INF 256
#define HF 64
#define OUTF 320           // 5 * 64
#define NB4 ((NN4 + 255) / 256)   // 49 blocks for packed node-range kernels
#define G 128              // histogram slices
#define SL (NE / G)        // 6250 edges per slice

typedef _Float16 half8 __attribute__((ext_vector_type(8)));
typedef float floatx4 __attribute__((ext_vector_type(4)));
typedef float f32x2 __attribute__((ext_vector_type(2)));
typedef float f32x4 __attribute__((ext_vector_type(4)));

// ---------------- fp16 helpers ----------------------------------------------
static __device__ __forceinline__ unsigned short f2h(float x) {
    _Float16 h = (_Float16)x;                 // v_cvt_f16_f32, RNE
    return *(unsigned short*)&h;
}
static __device__ __forceinline__ float h2f(unsigned short u) {
    _Float16 h = *(_Float16*)&u;
    return (float)h;                          // v_cvt_f32_f16
}

// ---------------- theta (computed on host each launch) ----------------------
struct ThetaM { float m[5][7]; };

static void compute_theta(ThetaM& tm) {
    const double e = 1.4;
    auto fact = [](int n) { double r = 1.0; for (int i = 2; i <= n; ++i) r *= i; return r; };
    for (int t = 0; t < 5; ++t) {
        int i = t + 2;              // i in [2,6]
        int mm = 6 - i;             // d - i + OFFSET
        double B = fact(i) * fact(6 - i) / fact(7);   // beta(i+1, 7-i)
        for (int k = 0; k < 7; ++k) tm.m[t][k] = 0.f;
        for (int j = 0; j <= mm; ++j) {
            double cb = fact(mm) / (fact(j) * fact(mm - j));
            double v = pow(1.0 / e, (double)i) * cb * pow(-1.0 / e, (double)j) / (e * B);
            tm.m[t][i + j] = (float)v;
        }
    }
}

// ---------------- zero deg + phantom g rows ---------------------------------
__global__ __launch_bounds__(1024) void zero_kernel(int* __restrict__ deg,
                                                    unsigned int* __restrict__ gA,
                                                    unsigned int* __restrict__ gB) {
    int i = blockIdx.x * 1024 + threadIdx.x;
    if (i < NN) deg[i] = 0;
    if (blockIdx.x == 0 && threadIdx.x < 32) {
        gA[NN * 32 + threadIdx.x] = 0u;     // phantom node row = 0 (padding target)
        gB[NN * 32 + threadIdx.x] = 0u;
    }
}

// ---------------- histogram of dst (u8 bins, LDS) + src degree (atomics) ----
__global__ __launch_bounds__(1024) void histdeg_kernel(const int* __restrict__ src,
                                                       const int* __restrict__ dst,
                                                       unsigned int* __restrict__ hist,
                                                       int* __restrict__ deg) {
    __shared__ unsigned int h[NN4];
    int b = blockIdx.x;
    for (int i = threadIdx.x; i < NN4; i += 1024) h[i] = 0u;
    __syncthreads();
    int base = b * SL;
    for (int i = threadIdx.x; i < SL; i += 1024) {
        int d = dst[base + i];
        atomicAdd(&h[d >> 2], 1u << ((d & 3) * 8));   // per-slice count < 256 (random data)
    }
    for (int i = threadIdx.x; i < SL; i += 1024) {
        atomicAdd(&deg[src[base + i]], 1);            // exact integer: order-independent
    }
    __syncthreads();
    unsigned int* out32 = hist + (size_t)b * NN4;
    for (int i = threadIdx.x; i < NN4; i += 1024) out32[i] = h[i];
}

// merge dst histograms (u8 packed, 4 nodes/thread): in-place exclusive per-slice
// offsets, real count, dinv from src degree, and per-block PADDED partial sums.
__global__ __launch_bounds__(256) void merge_dst_kernel(unsigned int* __restrict__ hist,
                                                        const int* __restrict__ deg,
                                                        int* __restrict__ cnt,
                                                        float* __restrict__ dinv,
                                                        int* __restrict__ partial) {
    __shared__ int s[256];
    int tid = threadIdx.x;
    int t = blockIdx.x * 256 + tid;     // packed index over NN4
    int run0 = 0, run1 = 0, run2 = 0, run3 = 0;
    if (t < NN4) {
        for (int b = 0; b < G; ++b) {
            size_t idx = (size_t)b * NN4 + t;
            unsigned int u = hist[idx];
            hist[idx] = (unsigned int)run0 | ((unsigned int)run1 << 8) |
                        ((unsigned int)run2 << 16) | ((unsigned int)run3 << 24);
            run0 += u & 255u; run1 += (u >> 8) & 255u;
            run2 += (u >> 16) & 255u; run3 += u >> 24;
        }
        *(int4*)&cnt[4 * t] = make_int4(run0, run1, run2, run3);
        int4 dg = *(const int4*)&deg[4 * t];
        float d0 = (float)(dg.x < 1 ? 1 : dg.x);
        float d1 = (float)(dg.y < 1 ? 1 : dg.y);
        float d2 = (float)(dg.z < 1 ? 1 : dg.z);
        float d3 = (float)(dg.w < 1 ? 1 : dg.w);
        *(float4*)&dinv[4 * t] = make_float4(1.0f / sqrtf(d0), 1.0f / sqrtf(d1),
                                             1.0f / sqrtf(d2), 1.0f / sqrtf(d3));
    }
    int pad = ((run0 + 3) & ~3) + ((run1 + 3) & ~3) + ((run2 + 3) & ~3) + ((run3 + 3) & ~3);
    s[tid] = pad;
    __syncthreads();
    for (int off = 128; off > 0; off >>= 1) {
        if (tid < off) s[tid] += s[tid + off];
        __syncthreads();
    }
    if (tid == 0) partial[blockIdx.x] = s[0];
}

__global__ __launch_bounds__(256) void scan_partials_kernel(const int* __restrict__ partial,
                                                            int* __restrict__ offsets,
                                                            int* __restrict__ row_ptr) {
    __shared__ int s[256];
    int tid = threadIdx.x;
    s[tid] = (tid < NB4) ? partial[tid] : 0;
    __syncthreads();
    for (int off = 1; off < 256; off <<= 1) {
        int t = (tid >= off) ? s[tid - off] : 0;
        __syncthreads();
        s[tid] += t;
        __syncthreads();
    }
    if (tid < NB4) offsets[tid] = (tid == 0) ? 0 : s[tid - 1];
    if (tid == NB4 - 1) row_ptr[NN] = s[tid];     // total PADDED edges
}

// row_ptr (padded, every row start % 4 == 0) + write phantom padding into col
__global__ __launch_bounds__(256) void scan_write_kernel(const int* __restrict__ cnt,
                                                         const int* __restrict__ offsets,
                                                         int* __restrict__ row_ptr,
                                                         int* __restrict__ col) {
    __shared__ int s[256];
    int tid = threadIdx.x;
    int t = blockIdx.x * 256 + tid;
    int4 c = make_int4(0, 0, 0, 0);
    if (t < NN4) c = *(const int4*)&cnt[4 * t];
    int p0 = (c.x + 3) & ~3, p1 = (c.y + 3) & ~3, p2 = (c.z + 3) & ~3, p3 = (c.w + 3) & ~3;
    int csum = p0 + p1 + p2 + p3;
    s[tid] = csum;
    __syncthreads();
    for (int off = 1; off < 256; off <<= 1) {
        int v = (tid >= off) ? s[tid - off] : 0;
        __syncthreads();
        s[tid] += v;
        __syncthreads();
    }
    if (t < NN4) {
        int b0 = offsets[blockIdx.x] + s[tid] - csum;
        int b1 = b0 + p0, b2 = b1 + p1, b3 = b2 + p2;
        *(int4*)&row_ptr[4 * t] = make_int4(b0, b1, b2, b3);
        for (int k = c.x; k < p0; ++k) col[b0 + k] = NN;   // phantom padding
        for (int k = c.y; k < p1; ++k) col[b1 + k] = NN;
        for (int k = c.z; k < p2; ++k) col[b2 + k] = NN;
        for (int k = c.w; k < p3; ++k) col[b3 + k] = NN;
    }
}

// ---- fill: deterministic placement, LDS-rank only, no global atomics -------
__global__ __launch_bounds__(1024) void fill_kernel(const int* __restrict__ src,
                                                    const int* __restrict__ dst,
                                                    const unsigned char* __restrict__ hist8,
                                                    const int* __restrict__ row_ptr,
                                                    int* __restrict__ col) {
    __shared__ unsigned int cur[NN4];
    int b = blockIdx.x;
    for (int i = threadIdx.x; i < NN4; i += 1024) cur[i] = 0u;
    __syncthreads();
    int base = b * SL;
    const unsigned char* hrow = hist8 + (size_t)b * NN;
    for (int i = threadIdx.x; i < SL; i += 1024) {
        int d = dst[base + i];
        int sh = (d & 3) * 8;
        unsigned int old = atomicAdd(&cur[d >> 2], 1u << sh);
        int rank = (int)((old >> sh) & 255u);
        int pos = row_ptr[d] + (int)hrow[d] + rank;
        col[pos] = src[base + i];
    }
}

// ---- W prep: Wt[n][k] = fp16(W[k][n]), 64 x 256 ----------------------------
__global__ __launch_bounds__(256) void wprep_kernel(const float* __restrict__ W,
                                                    unsigned short* __restrict__ Wt) {
    int id = blockIdx.x * 256 + threadIdx.x;   // over 64*256
    if (id >= HF * INF) return;
    int n = id >> 8;       // 0..63
    int k = id & 255;      // 0..255
    Wt[id] = f2h(W[k * HF + n]);
}

// ---- MFMA fp16 GEMM: h = leaky_relu(x @ W + b); f fp32; g fp16(h*dinv) -----
__global__ __launch_bounds__(256) void gemm_kernel(const float* __restrict__ x,
                                                   const unsigned short* __restrict__ Wt,
                                                   const float* __restrict__ b,
                                                   const float* __restrict__ dinv,
                                                   float* __restrict__ f,
                                                   unsigned short* __restrict__ g) {
    __shared__ _Float16 wls[64 * 264];   // row stride 264: banks +4/row
    __shared__ _Float16 xls[64 * 136];   // row stride 136: banks +4/row
    int tid = threadIdx.x;
    int row0 = blockIdx.x * 64;
    int wave = tid >> 6;
    int lane = tid & 63;
    int q = lane >> 4;        // quad 0..3
    int ln = lane & 15;

    // stage Wt: 64 rows x 32 x 16B chunks = 2048 chunks
    {
        const uint4* wg = (const uint4*)Wt;
        for (int i = 0; i < 8; ++i) {
            int l = tid + i * 256;
            int r = l >> 5, c = l & 31;
            *(uint4*)&wls[r * 264 + c * 8] = wg[l];
        }
    }

    floatx4 acc[4] = {{0.f,0.f,0.f,0.f},{0.f,0.f,0.f,0.f},{0.f,0.f,0.f,0.f},{0.f,0.f,0.f,0.f}};

    for (int ch = 0; ch < 2; ++ch) {
        __syncthreads();   // protect xls reuse (and Wt on first pass)
        for (int i = 0; i < 8; ++i) {
            int l = tid + i * 256;
            int r = l >> 5, c4 = (l & 31) * 4;
            int grow = row0 + r;
            f32x4 v = {0.f, 0.f, 0.f, 0.f};
            if (grow < NN) v = __builtin_nontemporal_load((const f32x4*)&x[(size_t)grow * INF + ch * 128 + c4]);
            ushort4 hv;
            hv.x = f2h(v[0]); hv.y = f2h(v[1]); hv.z = f2h(v[2]); hv.w = f2h(v[3]);
            *(ushort4*)&xls[r * 136 + c4] = hv;
        }
        __syncthreads();
        int m = wave * 16 + ln;
        #pragma unroll
        for (int kb4 = 0; kb4 < 4; ++kb4) {
            int kb = kb4 * 32;
            half8 a = *(const half8*)&xls[m * 136 + kb + q * 8];
            int kg = ch * 128 + kb + q * 8;
            #pragma unroll
            for (int t = 0; t < 4; ++t) {
                half8 bb = *(const half8*)&wls[(t * 16 + ln) * 264 + kg];
                acc[t] = __builtin_amdgcn_mfma_f32_16x16x32_f16(a, bb, acc[t], 0, 0, 0);
            }
        }
    }

    // epilogue: lane holds rows wave*16 + q*4 + r, col t*16 + ln
    float bias[4];
    #pragma unroll
    for (int t = 0; t < 4; ++t) bias[t] = b[t * 16 + ln];
    #pragma unroll
    for (int r = 0; r < 4; ++r) {
        int grow = row0 + wave * 16 + q * 4 + r;
        if (grow < NN) {
            float dv = dinv[grow];
            #pragma unroll
            for (int t = 0; t < 4; ++t) {
                float h = acc[t][r] + bias[t];
                h = (h > 0.f) ? h : 0.01f * h;
                int cidx = t * 16 + ln;
                f[(size_t)grow * HF + cidx] = h;
                g[(size_t)grow * HF + cidx] = f2h(h * dv);
            }
        }
    }
}

// prop: 32 lanes per node (2 nodes/wave), lane handles feature pair 2c,2c+1.
// rows padded to x4 with phantom node NN (g row = 0): int4 col loads, no
// scalar remainder, 16B-aligned row starts.
__global__ __launch_bounds__(256) void prop_kernel(const int* __restrict__ row_ptr,
                                                   const int* __restrict__ col,
                                                   const float* __restrict__ dinv,
                                                   const unsigned int* __restrict__ g_in,
                                                   const float* __restrict__ f_in, int fin_stride,
                                                   float* __restrict__ f_out, int fout_stride,
                                                   unsigned int* __restrict__ g_out) {
    int gidx = blockIdx.x * 256 + threadIdx.x;
    int wid = gidx >> 5;              // node
    int c2 = threadIdx.x & 31;        // feature pair
    if (wid >= NN) return;
    int j   = row_ptr[wid];
    int end = row_ptr[wid + 1];
    float s0 = 0.f, s1 = 0.f;
    for (; j + 8 <= end; j += 8) {
        int4 ca = *(const int4*)&col[j];
        int4 cb = *(const int4*)&col[j + 4];
        unsigned int u0 = g_in[ca.x * 32 + c2];
        unsigned int u1 = g_in[ca.y * 32 + c2];
        unsigned int u2 = g_in[ca.z * 32 + c2];
        unsigned int u3 = g_in[ca.w * 32 + c2];
        unsigned int u4 = g_in[cb.x * 32 + c2];
        unsigned int u5 = g_in[cb.y * 32 + c2];
        unsigned int u6 = g_in[cb.z * 32 + c2];
        unsigned int u7 = g_in[cb.w * 32 + c2];
        s0 += ((h2f(u0 & 0xFFFF) + h2f(u1 & 0xFFFF)) + (h2f(u2 & 0xFFFF) + h2f(u3 & 0xFFFF)))
            + ((h2f(u4 & 0xFFFF) + h2f(u5 & 0xFFFF)) + (h2f(u6 & 0xFFFF) + h2f(u7 & 0xFFFF)));
        s1 += ((h2f(u0 >> 16) + h2f(u1 >> 16)) + (h2f(u2 >> 16) + h2f(u3 >> 16)))
            + ((h2f(u4 >> 16) + h2f(u5 >> 16)) + (h2f(u6 >> 16) + h2f(u7 >> 16)));
    }
    if (j < end) {   // exactly 4 remain (rows are multiples of 4)
        int4 ca = *(const int4*)&col[j];
        unsigned int u0 = g_in[ca.x * 32 + c2];
        unsigned int u1 = g_in[ca.y * 32 + c2];
        unsigned int u2 = g_in[ca.z * 32 + c2];
        unsigned int u3 = g_in[ca.w * 32 + c2];
        s0 += (h2f(u0 & 0xFFFF) + h2f(u1 & 0xFFFF)) + (h2f(u2 & 0xFFFF) + h2f(u3 & 0xFFFF));
        s1 += (h2f(u0 >> 16) + h2f(u1 >> 16)) + (h2f(u2 >> 16) + h2f(u3 >> 16));
    }
    float dv = dinv[wid];
    f32x2 fv = __builtin_nontemporal_load((const f32x2*)&f_in[(size_t)wid * fin_stride + 2 * c2]);
    float fx = fv[0] - s0 * dv;
    float fy = fv[1] - s1 * dv;
    f32x2 ov; ov[0] = fx; ov[1] = fy;
    __builtin_nontemporal_store(ov, (f32x2*)&f_out[(size_t)wid * fout_stride + 2 * c2]);
    if (g_out) g_out[wid * 32 + c2] = (unsigned int)f2h(fx * dv) | ((unsigned int)f2h(fy * dv) << 16);
}

// out slot t currently holds f_{t+2}; apply upper-triangular theta combo in place
__global__ __launch_bounds__(256) void final_kernel(float* __restrict__ out, ThetaM tm) {
    int idx = blockIdx.x * 256 + threadIdx.x;          // over NN*32
    if (idx >= NN * 32) return;
    int n = idx >> 5;
    int c = (idx & 31) * 2;
    f32x2 v[5];
    #pragma unroll
    for (int j = 0; j < 5; ++j)
        v[j] = __builtin_nontemporal_load((const f32x2*)&out[(size_t)n * OUTF + j * HF + c]);
    #pragma unroll
    for (int t = 0; t < 5; ++t) {
        f32x2 o = {0.f, 0.f};
        #pragma unroll
        for (int j = 0; j < 5; ++j) {
            if (j >= t) { o[0] += tm.m[t][j + 2] * v[j][0]; o[1] += tm.m[t][j + 2] * v[j][1]; }
        }
        __builtin_nontemporal_store(o, (f32x2*)&out[(size_t)n * OUTF + t * HF + c]);
    }
}

// ---------------- launch -----------------------------------------------------
extern "C" void kernel_launch(void* const* d_in, const int* in_sizes, int n_in,
                              void* d_out, int out_size, void* d_ws, size_t ws_size,
                              hipStream_t stream) {
    const float* x  = (const float*)d_in[0];
    const float* W  = (const float*)d_in[1];
    const float* b  = (const float*)d_in[2];
    const int* src  = (const int*)d_in[3];
    const int* dst  = (const int*)d_in[4];
    float* out = (float*)d_out;

    char* ws = (char*)d_ws;
    size_t off = 0;
    auto alloc = [&](size_t bytes) -> void* {
        void* p = ws + off;
        off += (bytes + 255) & ~(size_t)255;
        return p;
    };
    unsigned int* hist_dst = (unsigned int*)alloc((size_t)G * NN4 * 4);   // 6.4MB u8-packed
    int*   deg     = (int*)alloc((size_t)NN * 4);
    int*   cnt     = (int*)alloc((size_t)NN * 4);
    int*   row_ptr = (int*)alloc((size_t)(NN + 1) * 4);
    int*   partial = (int*)alloc((size_t)NB4 * 4);
    int*   offsets = (int*)alloc((size_t)NB4 * 4);
    float* dinv    = (float*)alloc((size_t)NN * 4);
    int*   col     = (int*)alloc((size_t)(NE + 4 * NN) * 4);              // padded CSR
    unsigned short* wt = (unsigned short*)alloc((size_t)HF * INF * 2);
    float* fbuf    = (float*)alloc((size_t)NN * HF * 4);
    unsigned short* gA = (unsigned short*)alloc((size_t)(NN + 1) * HF * 2);  // +phantom row
    unsigned short* gB = (unsigned short*)alloc((size_t)(NN + 1) * HF * 2);

    zero_kernel<<<(NN + 1023) / 1024, 1024, 0, stream>>>(deg, (unsigned int*)gA, (unsigned int*)gB);
    histdeg_kernel<<<G, 1024, 0, stream>>>(src, dst, hist_dst, deg);
    merge_dst_kernel<<<NB4, 256, 0, stream>>>(hist_dst, deg, cnt, dinv, partial);
    scan_partials_kernel<<<1, 256, 0, stream>>>(partial, offsets, row_ptr);
    scan_write_kernel<<<NB4, 256, 0, stream>>>(cnt, offsets, row_ptr, col);
    fill_kernel<<<G, 1024, 0, stream>>>(src, dst, (const unsigned char*)hist_dst, row_ptr, col);
    wprep_kernel<<<(HF * INF + 255) / 256, 256, 0, stream>>>(W, wt);
    gemm_kernel<<<(NN + 63) / 64, 256, 0, stream>>>(x, wt, b, dinv, fbuf, gA);

    const int PB = (NN * 32 + 255) / 256;
    // k=1: f stays in fbuf; g: gA -> gB
    prop_kernel<<<PB, 256, 0, stream>>>(row_ptr, col, dinv, (unsigned int*)gA, fbuf, HF, fbuf, HF, (unsigned int*)gB);
    // k=2: f: fbuf -> slot0; g: gB -> gA
    prop_kernel<<<PB, 256, 0, stream>>>(row_ptr, col, dinv, (unsigned int*)gB, fbuf, HF, out + 0 * HF, OUTF, (unsigned int*)gA);
    // k=3: slot0 -> slot1; g: gA -> gB
    prop_kernel<<<PB, 256, 0, stream>>>(row_ptr, col, dinv, (unsigned int*)gA, out + 0 * HF, OUTF, out + 1 * HF, OUTF, (unsigned int*)gB);
    // k=4: slot1 -> slot2; g: gB -> gA
    prop_kernel<<<PB, 256, 0, stream>>>(row_ptr, col, dinv, (unsigned int*)gB, out + 1 * HF, OUTF, out + 2 * HF, OUTF, (unsigned int*)gA);
    // k=5: slot2 -> slot3; g: gA -> gB
    prop_kernel<<<PB, 256, 0, stream>>>(row_ptr, col, dinv, (unsigned int*)gA, out + 2 * HF, OUTF, out + 3 * HF, OUTF, (unsigned int*)gB);
    // k=6: slot3 -> slot4; g unused
    prop_kernel<<<PB, 256, 0, stream>>>(row_ptr, col, dinv, (unsigned int*)gB, out + 3 * HF, OUTF, out + 4 * HF, OUTF, nullptr);

    ThetaM tm;
    compute_theta(tm);
    final_kernel<<<(NN * 32 + 255) / 256, 256, 0, stream>>>(out, tm);
}

// Round 4
// 329.353 us; speedup vs baseline: 1.0844x; 1.0844x over previous
//
#include <hip/hip_runtime.h>
#include <math.h>

#define NN 50000
#define NN4 12500          // NN/4 packed u8 bins (u32 words)
#define NE 800000
#define INF 256
#define HF 64
#define OUTF 320           // 5 * 64
#define NB4 ((NN4 + 255) / 256)   // 49 blocks for packed node-range kernels
#define G 128              // histogram slices
#define SL (NE / G)        // 6250 edges per slice

typedef _Float16 half8 __attribute__((ext_vector_type(8)));
typedef float floatx4 __attribute__((ext_vector_type(4)));
typedef float f32x2 __attribute__((ext_vector_type(2)));
typedef float f32x4 __attribute__((ext_vector_type(4)));

// ---------------- fp16 helpers ----------------------------------------------
static __device__ __forceinline__ unsigned short f2h(float x) {
    _Float16 h = (_Float16)x;                 // v_cvt_f16_f32, RNE
    return *(unsigned short*)&h;
}
static __device__ __forceinline__ float h2f(unsigned short u) {
    _Float16 h = *(_Float16*)&u;
    return (float)h;                          // v_cvt_f32_f16
}

// ---------------- theta (computed on host each launch) ----------------------
struct ThetaM { float m[5][7]; };

static void compute_theta(ThetaM& tm) {
    const double e = 1.4;
    auto fact = [](int n) { double r = 1.0; for (int i = 2; i <= n; ++i) r *= i; return r; };
    for (int t = 0; t < 5; ++t) {
        int i = t + 2;              // i in [2,6]
        int mm = 6 - i;             // d - i + OFFSET
        double B = fact(i) * fact(6 - i) / fact(7);   // beta(i+1, 7-i)
        for (int k = 0; k < 7; ++k) tm.m[t][k] = 0.f;
        for (int j = 0; j <= mm; ++j) {
            double cb = fact(mm) / (fact(j) * fact(mm - j));
            double v = pow(1.0 / e, (double)i) * cb * pow(-1.0 / e, (double)j) / (e * B);
            tm.m[t][i + j] = (float)v;
        }
    }
}

// ---------------- zero phantom g rows (deg atomics removed) ------------------
__global__ __launch_bounds__(64) void zero_kernel(unsigned int* __restrict__ gA,
                                                  unsigned int* __restrict__ gB) {
    if (threadIdx.x < 32) {
        gA[NN * 32 + threadIdx.x] = 0u;     // phantom node row = 0 (padding target)
        gB[NN * 32 + threadIdx.x] = 0u;
    }
}

// ------ split histograms: blocks 0..G-1 dst, G..2G-1 src; u8 LDS bins -------
// No global atomics: WRITE_SIZE = 2 * 6.4 MB of clean streaming writes.
__global__ __launch_bounds__(1024) void hist_kernel(const int* __restrict__ src,
                                                    const int* __restrict__ dst,
                                                    unsigned int* __restrict__ hist_dst,
                                                    unsigned int* __restrict__ hist_src) {
    __shared__ unsigned int h[NN4];
    int b = blockIdx.x;
    const int* arr = (b < G) ? dst : src;
    unsigned int* outp = (b < G) ? hist_dst : hist_src;
    int bb = (b < G) ? b : b - G;
    for (int i = threadIdx.x; i < NN4; i += 1024) h[i] = 0u;
    __syncthreads();
    int base = bb * SL;
    for (int i = threadIdx.x; i < SL; i += 1024) {
        int d = arr[base + i];
        atomicAdd(&h[d >> 2], 1u << ((d & 3) * 8));   // per-slice count << 256 (random data)
    }
    __syncthreads();
    unsigned int* out32 = outp + (size_t)bb * NN4;
    for (int i = threadIdx.x; i < NN4; i += 1024) out32[i] = h[i];
}

// merge (u8 packed, 4 nodes/thread): dst -> in-place exclusive per-slice
// offsets + real count + padded partials; src -> degree sum -> dinv. Fused.
__global__ __launch_bounds__(256) void merge_kernel(unsigned int* __restrict__ hist_dst,
                                                    const unsigned int* __restrict__ hist_src,
                                                    int* __restrict__ cnt,
                                                    float* __restrict__ dinv,
                                                    int* __restrict__ partial) {
    __shared__ int s[256];
    int tid = threadIdx.x;
    int t = blockIdx.x * 256 + tid;     // packed index over NN4
    int run0 = 0, run1 = 0, run2 = 0, run3 = 0;
    if (t < NN4) {
        for (int b = 0; b < G; ++b) {
            size_t idx = (size_t)b * NN4 + t;
            unsigned int u = hist_dst[idx];
            hist_dst[idx] = (unsigned int)run0 | ((unsigned int)run1 << 8) |
                            ((unsigned int)run2 << 16) | ((unsigned int)run3 << 24);
            run0 += u & 255u; run1 += (u >> 8) & 255u;
            run2 += (u >> 16) & 255u; run3 += u >> 24;
        }
        *(int4*)&cnt[4 * t] = make_int4(run0, run1, run2, run3);
        // src degree: sum u8 lanes over G slices
        int d0 = 0, d1 = 0, d2 = 0, d3 = 0;
        for (int b = 0; b < G; ++b) {
            unsigned int u = hist_src[(size_t)b * NN4 + t];
            d0 += u & 255u; d1 += (u >> 8) & 255u;
            d2 += (u >> 16) & 255u; d3 += u >> 24;
        }
        float e0 = (float)(d0 < 1 ? 1 : d0);
        float e1 = (float)(d1 < 1 ? 1 : d1);
        float e2 = (float)(d2 < 1 ? 1 : d2);
        float e3 = (float)(d3 < 1 ? 1 : d3);
        *(float4*)&dinv[4 * t] = make_float4(1.0f / sqrtf(e0), 1.0f / sqrtf(e1),
                                             1.0f / sqrtf(e2), 1.0f / sqrtf(e3));
    }
    int pad = ((run0 + 3) & ~3) + ((run1 + 3) & ~3) + ((run2 + 3) & ~3) + ((run3 + 3) & ~3);
    s[tid] = pad;
    __syncthreads();
    for (int off = 128; off > 0; off >>= 1) {
        if (tid < off) s[tid] += s[tid + off];
        __syncthreads();
    }
    if (tid == 0) partial[blockIdx.x] = s[0];
}

__global__ __launch_bounds__(256) void scan_partials_kernel(const int* __restrict__ partial,
                                                            int* __restrict__ offsets,
                                                            int* __restrict__ row_ptr) {
    __shared__ int s[256];
    int tid = threadIdx.x;
    s[tid] = (tid < NB4) ? partial[tid] : 0;
    __syncthreads();
    for (int off = 1; off < 256; off <<= 1) {
        int t = (tid >= off) ? s[tid - off] : 0;
        __syncthreads();
        s[tid] += t;
        __syncthreads();
    }
    if (tid < NB4) offsets[tid] = (tid == 0) ? 0 : s[tid - 1];
    if (tid == NB4 - 1) row_ptr[NN] = s[tid];     // total PADDED edges
}

// row_ptr (padded, every row start % 4 == 0) + write phantom padding into col
__global__ __launch_bounds__(256) void scan_write_kernel(const int* __restrict__ cnt,
                                                         const int* __restrict__ offsets,
                                                         int* __restrict__ row_ptr,
                                                         int* __restrict__ col) {
    __shared__ int s[256];
    int tid = threadIdx.x;
    int t = blockIdx.x * 256 + tid;
    int4 c = make_int4(0, 0, 0, 0);
    if (t < NN4) c = *(const int4*)&cnt[4 * t];
    int p0 = (c.x + 3) & ~3, p1 = (c.y + 3) & ~3, p2 = (c.z + 3) & ~3, p3 = (c.w + 3) & ~3;
    int csum = p0 + p1 + p2 + p3;
    s[tid] = csum;
    __syncthreads();
    for (int off = 1; off < 256; off <<= 1) {
        int v = (tid >= off) ? s[tid - off] : 0;
        __syncthreads();
        s[tid] += v;
        __syncthreads();
    }
    if (t < NN4) {
        int b0 = offsets[blockIdx.x] + s[tid] - csum;
        int b1 = b0 + p0, b2 = b1 + p1, b3 = b2 + p2;
        *(int4*)&row_ptr[4 * t] = make_int4(b0, b1, b2, b3);
        for (int k = c.x; k < p0; ++k) col[b0 + k] = NN;   // phantom padding
        for (int k = c.y; k < p1; ++k) col[b1 + k] = NN;
        for (int k = c.z; k < p2; ++k) col[b2 + k] = NN;
        for (int k = c.w; k < p3; ++k) col[b3 + k] = NN;
    }
}

// ---- fill: deterministic placement, LDS-rank only, no global atomics -------
__global__ __launch_bounds__(1024) void fill_kernel(const int* __restrict__ src,
                                                    const int* __restrict__ dst,
                                                    const unsigned char* __restrict__ hist8,
                                                    const int* __restrict__ row_ptr,
                                                    int* __restrict__ col) {
    __shared__ unsigned int cur[NN4];
    int b = blockIdx.x;
    for (int i = threadIdx.x; i < NN4; i += 1024) cur[i] = 0u;
    __syncthreads();
    int base = b * SL;
    const unsigned char* hrow = hist8 + (size_t)b * NN;
    for (int i = threadIdx.x; i < SL; i += 1024) {
        int d = dst[base + i];
        int sh = (d & 3) * 8;
        unsigned int old = atomicAdd(&cur[d >> 2], 1u << sh);
        int rank = (int)((old >> sh) & 255u);
        int pos = row_ptr[d] + (int)hrow[d] + rank;
        col[pos] = src[base + i];
    }
}

// ---- W prep: Wt[n][k] = fp16(W[k][n]), 64 x 256 ----------------------------
__global__ __launch_bounds__(256) void wprep_kernel(const float* __restrict__ W,
                                                    unsigned short* __restrict__ Wt) {
    int id = blockIdx.x * 256 + threadIdx.x;   // over 64*256
    if (id >= HF * INF) return;
    int n = id >> 8;       // 0..63
    int k = id & 255;      // 0..255
    Wt[id] = f2h(W[k * HF + n]);
}

// ---- MFMA fp16 GEMM: h = leaky_relu(x @ W + b); f fp32; g fp16(h*dinv) -----
__global__ __launch_bounds__(256) void gemm_kernel(const float* __restrict__ x,
                                                   const unsigned short* __restrict__ Wt,
                                                   const float* __restrict__ b,
                                                   const float* __restrict__ dinv,
                                                   float* __restrict__ f,
                                                   unsigned short* __restrict__ g) {
    __shared__ _Float16 wls[64 * 264];   // row stride 264: banks +4/row
    __shared__ _Float16 xls[64 * 136];   // row stride 136: banks +4/row
    int tid = threadIdx.x;
    int row0 = blockIdx.x * 64;
    int wave = tid >> 6;
    int lane = tid & 63;
    int q = lane >> 4;        // quad 0..3
    int ln = lane & 15;

    // stage Wt: 64 rows x 32 x 16B chunks = 2048 chunks
    {
        const uint4* wg = (const uint4*)Wt;
        for (int i = 0; i < 8; ++i) {
            int l = tid + i * 256;
            int r = l >> 5, c = l & 31;
            *(uint4*)&wls[r * 264 + c * 8] = wg[l];
        }
    }

    floatx4 acc[4] = {{0.f,0.f,0.f,0.f},{0.f,0.f,0.f,0.f},{0.f,0.f,0.f,0.f},{0.f,0.f,0.f,0.f}};

    for (int ch = 0; ch < 2; ++ch) {
        __syncthreads();   // protect xls reuse (and Wt on first pass)
        for (int i = 0; i < 8; ++i) {
            int l = tid + i * 256;
            int r = l >> 5, c4 = (l & 31) * 4;
            int grow = row0 + r;
            f32x4 v = {0.f, 0.f, 0.f, 0.f};
            if (grow < NN) v = __builtin_nontemporal_load((const f32x4*)&x[(size_t)grow * INF + ch * 128 + c4]);
            ushort4 hv;
            hv.x = f2h(v[0]); hv.y = f2h(v[1]); hv.z = f2h(v[2]); hv.w = f2h(v[3]);
            *(ushort4*)&xls[r * 136 + c4] = hv;
        }
        __syncthreads();
        int m = wave * 16 + ln;
        #pragma unroll
        for (int kb4 = 0; kb4 < 4; ++kb4) {
            int kb = kb4 * 32;
            half8 a = *(const half8*)&xls[m * 136 + kb + q * 8];
            int kg = ch * 128 + kb + q * 8;
            #pragma unroll
            for (int t = 0; t < 4; ++t) {
                half8 bb = *(const half8*)&wls[(t * 16 + ln) * 264 + kg];
                acc[t] = __builtin_amdgcn_mfma_f32_16x16x32_f16(a, bb, acc[t], 0, 0, 0);
            }
        }
    }

    // epilogue: lane holds rows wave*16 + q*4 + r, col t*16 + ln
    float bias[4];
    #pragma unroll
    for (int t = 0; t < 4; ++t) bias[t] = b[t * 16 + ln];
    #pragma unroll
    for (int r = 0; r < 4; ++r) {
        int grow = row0 + wave * 16 + q * 4 + r;
        if (grow < NN) {
            float dv = dinv[grow];
            #pragma unroll
            for (int t = 0; t < 4; ++t) {
                float h = acc[t][r] + bias[t];
                h = (h > 0.f) ? h : 0.01f * h;
                int cidx = t * 16 + ln;
                f[(size_t)grow * HF + cidx] = h;
                g[(size_t)grow * HF + cidx] = f2h(h * dv);
            }
        }
    }
}

// prop: 32 lanes per node (2 nodes/wave), lane handles feature pair 2c,2c+1.
// rows padded to x4 with phantom node NN (g row = 0): int4 col loads, no
// scalar remainder, 16B-aligned row starts.
__global__ __launch_bounds__(256) void prop_kernel(const int* __restrict__ row_ptr,
                                                   const int* __restrict__ col,
                                                   const float* __restrict__ dinv,
                                                   const unsigned int* __restrict__ g_in,
                                                   const float* __restrict__ f_in, int fin_stride,
                                                   float* __restrict__ f_out, int fout_stride,
                                                   unsigned int* __restrict__ g_out) {
    int gidx = blockIdx.x * 256 + threadIdx.x;
    int wid = gidx >> 5;              // node
    int c2 = threadIdx.x & 31;        // feature pair
    if (wid >= NN) return;
    int j   = row_ptr[wid];
    int end = row_ptr[wid + 1];
    float s0 = 0.f, s1 = 0.f;
    for (; j + 8 <= end; j += 8) {
        int4 ca = *(const int4*)&col[j];
        int4 cb = *(const int4*)&col[j + 4];
        unsigned int u0 = g_in[ca.x * 32 + c2];
        unsigned int u1 = g_in[ca.y * 32 + c2];
        unsigned int u2 = g_in[ca.z * 32 + c2];
        unsigned int u3 = g_in[ca.w * 32 + c2];
        unsigned int u4 = g_in[cb.x * 32 + c2];
        unsigned int u5 = g_in[cb.y * 32 + c2];
        unsigned int u6 = g_in[cb.z * 32 + c2];
        unsigned int u7 = g_in[cb.w * 32 + c2];
        s0 += ((h2f(u0 & 0xFFFF) + h2f(u1 & 0xFFFF)) + (h2f(u2 & 0xFFFF) + h2f(u3 & 0xFFFF)))
            + ((h2f(u4 & 0xFFFF) + h2f(u5 & 0xFFFF)) + (h2f(u6 & 0xFFFF) + h2f(u7 & 0xFFFF)));
        s1 += ((h2f(u0 >> 16) + h2f(u1 >> 16)) + (h2f(u2 >> 16) + h2f(u3 >> 16)))
            + ((h2f(u4 >> 16) + h2f(u5 >> 16)) + (h2f(u6 >> 16) + h2f(u7 >> 16)));
    }
    if (j < end) {   // exactly 4 remain (rows are multiples of 4)
        int4 ca = *(const int4*)&col[j];
        unsigned int u0 = g_in[ca.x * 32 + c2];
        unsigned int u1 = g_in[ca.y * 32 + c2];
        unsigned int u2 = g_in[ca.z * 32 + c2];
        unsigned int u3 = g_in[ca.w * 32 + c2];
        s0 += (h2f(u0 & 0xFFFF) + h2f(u1 & 0xFFFF)) + (h2f(u2 & 0xFFFF) + h2f(u3 & 0xFFFF));
        s1 += (h2f(u0 >> 16) + h2f(u1 >> 16)) + (h2f(u2 >> 16) + h2f(u3 >> 16));
    }
    float dv = dinv[wid];
    f32x2 fv = __builtin_nontemporal_load((const f32x2*)&f_in[(size_t)wid * fin_stride + 2 * c2]);
    float fx = fv[0] - s0 * dv;
    float fy = fv[1] - s1 * dv;
    f32x2 ov; ov[0] = fx; ov[1] = fy;
    __builtin_nontemporal_store(ov, (f32x2*)&f_out[(size_t)wid * fout_stride + 2 * c2]);
    if (g_out) g_out[wid * 32 + c2] = (unsigned int)f2h(fx * dv) | ((unsigned int)f2h(fy * dv) << 16);
}

// out slot t currently holds f_{t+2}; apply upper-triangular theta combo in place
__global__ __launch_bounds__(256) void final_kernel(float* __restrict__ out, ThetaM tm) {
    int idx = blockIdx.x * 256 + threadIdx.x;          // over NN*32
    if (idx >= NN * 32) return;
    int n = idx >> 5;
    int c = (idx & 31) * 2;
    f32x2 v[5];
    #pragma unroll
    for (int j = 0; j < 5; ++j)
        v[j] = __builtin_nontemporal_load((const f32x2*)&out[(size_t)n * OUTF + j * HF + c]);
    #pragma unroll
    for (int t = 0; t < 5; ++t) {
        f32x2 o = {0.f, 0.f};
        #pragma unroll
        for (int j = 0; j < 5; ++j) {
            if (j >= t) { o[0] += tm.m[t][j + 2] * v[j][0]; o[1] += tm.m[t][j + 2] * v[j][1]; }
        }
        __builtin_nontemporal_store(o, (f32x2*)&out[(size_t)n * OUTF + t * HF + c]);
    }
}

// ---------------- launch -----------------------------------------------------
extern "C" void kernel_launch(void* const* d_in, const int* in_sizes, int n_in,
                              void* d_out, int out_size, void* d_ws, size_t ws_size,
                              hipStream_t stream) {
    const float* x  = (const float*)d_in[0];
    const float* W  = (const float*)d_in[1];
    const float* b  = (const float*)d_in[2];
    const int* src  = (const int*)d_in[3];
    const int* dst  = (const int*)d_in[4];
    float* out = (float*)d_out;

    char* ws = (char*)d_ws;
    size_t off = 0;
    auto alloc = [&](size_t bytes) -> void* {
        void* p = ws + off;
        off += (bytes + 255) & ~(size_t)255;
        return p;
    };
    unsigned int* hist_dst = (unsigned int*)alloc((size_t)G * NN4 * 4);   // 6.4MB u8-packed
    unsigned int* hist_src = (unsigned int*)alloc((size_t)G * NN4 * 4);   // 6.4MB u8-packed
    int*   cnt     = (int*)alloc((size_t)NN * 4);
    int*   row_ptr = (int*)alloc((size_t)(NN + 1) * 4);
    int*   partial = (int*)alloc((size_t)NB4 * 4);
    int*   offsets = (int*)alloc((size_t)NB4 * 4);
    float* dinv    = (float*)alloc((size_t)NN * 4);
    int*   col     = (int*)alloc((size_t)(NE + 4 * NN) * 4);              // padded CSR
    unsigned short* wt = (unsigned short*)alloc((size_t)HF * INF * 2);
    float* fbuf    = (float*)alloc((size_t)NN * HF * 4);
    unsigned short* gA = (unsigned short*)alloc((size_t)(NN + 1) * HF * 2);  // +phantom row
    unsigned short* gB = (unsigned short*)alloc((size_t)(NN + 1) * HF * 2);

    zero_kernel<<<1, 64, 0, stream>>>((unsigned int*)gA, (unsigned int*)gB);
    hist_kernel<<<2 * G, 1024, 0, stream>>>(src, dst, hist_dst, hist_src);
    merge_kernel<<<NB4, 256, 0, stream>>>(hist_dst, hist_src, cnt, dinv, partial);
    scan_partials_kernel<<<1, 256, 0, stream>>>(partial, offsets, row_ptr);
    scan_write_kernel<<<NB4, 256, 0, stream>>>(cnt, offsets, row_ptr, col);
    fill_kernel<<<G, 1024, 0, stream>>>(src, dst, (const unsigned char*)hist_dst, row_ptr, col);
    wprep_kernel<<<(HF * INF + 255) / 256, 256, 0, stream>>>(W, wt);
    gemm_kernel<<<(NN + 63) / 64, 256, 0, stream>>>(x, wt, b, dinv, fbuf, gA);

    const int PB = (NN * 32 + 255) / 256;
    // k=1: f stays in fbuf; g: gA -> gB
    prop_kernel<<<PB, 256, 0, stream>>>(row_ptr, col, dinv, (unsigned int*)gA, fbuf, HF, fbuf, HF, (unsigned int*)gB);
    // k=2: f: fbuf -> slot0; g: gB -> gA
    prop_kernel<<<PB, 256, 0, stream>>>(row_ptr, col, dinv, (unsigned int*)gB, fbuf, HF, out + 0 * HF, OUTF, (unsigned int*)gA);
    // k=3: slot0 -> slot1; g: gA -> gB
    prop_kernel<<<PB, 256, 0, stream>>>(row_ptr, col, dinv, (unsigned int*)gA, out + 0 * HF, OUTF, out + 1 * HF, OUTF, (unsigned int*)gB);
    // k=4: slot1 -> slot2; g: gB -> gA
    prop_kernel<<<PB, 256, 0, stream>>>(row_ptr, col, dinv, (unsigned int*)gB, out + 1 * HF, OUTF, out + 2 * HF, OUTF, (unsigned int*)gA);
    // k=5: slot2 -> slot3; g: gA -> gB
    prop_kernel<<<PB, 256, 0, stream>>>(row_ptr, col, dinv, (unsigned int*)gA, out + 2 * HF, OUTF, out + 3 * HF, OUTF, (unsigned int*)gB);
    // k=6: slot3 -> slot4; g unused
    prop_kernel<<<PB, 256, 0, stream>>>(row_ptr, col, dinv, (unsigned int*)gB, out + 3 * HF, OUTF, out + 4 * HF, OUTF, nullptr);

    ThetaM tm;
    compute_theta(tm);
    final_kernel<<<(NN * 32 + 255) / 256, 256, 0, stream>>>(out, tm);
}

// Round 5
// 302.294 us; speedup vs baseline: 1.1815x; 1.0895x over previous
//
#include <hip/hip_runtime.h>
#include <math.h>

#define NN 50000
#define NN4 12500          // NN/4 packed u8 bins (u32 words)
#define NE 800000
#define INF 256
#define HF 64
#define OUTF 320           // 5 * 64
#define NB4 ((NN4 + 255) / 256)   // 49 blocks for packed node-range kernels
#define G 128              // histogram slices
#define SL (NE / G)        // 6250 edges per slice

typedef _Float16 half8 __attribute__((ext_vector_type(8)));
typedef float floatx4 __attribute__((ext_vector_type(4)));
typedef float f32x2 __attribute__((ext_vector_type(2)));
typedef float f32x4 __attribute__((ext_vector_type(4)));

// ---------------- fp16 helpers ----------------------------------------------
static __device__ __forceinline__ unsigned short f2h(float x) {
    _Float16 h = (_Float16)x;                 // v_cvt_f16_f32, RNE
    return *(unsigned short*)&h;
}
static __device__ __forceinline__ float h2f(unsigned short u) {
    _Float16 h = *(_Float16*)&u;
    return (float)h;                          // v_cvt_f32_f16
}

// ---------------- theta (computed on host each launch) ----------------------
struct ThetaM { float m[5][7]; };

static void compute_theta(ThetaM& tm) {
    const double e = 1.4;
    auto fact = [](int n) { double r = 1.0; for (int i = 2; i <= n; ++i) r *= i; return r; };
    for (int t = 0; t < 5; ++t) {
        int i = t + 2;              // i in [2,6]
        int mm = 6 - i;             // d - i + OFFSET
        double B = fact(i) * fact(6 - i) / fact(7);   // beta(i+1, 7-i)
        for (int k = 0; k < 7; ++k) tm.m[t][k] = 0.f;
        for (int j = 0; j <= mm; ++j) {
            double cb = fact(mm) / (fact(j) * fact(mm - j));
            double v = pow(1.0 / e, (double)i) * cb * pow(-1.0 / e, (double)j) / (e * B);
            tm.m[t][i + j] = (float)v;
        }
    }
}

// ------ split histograms: blocks 0..G-1 dst, G..2G-1 src; u8 LDS bins -------
// Also zeroes the phantom g rows (blocks 0 and 1) - no separate zero kernel.
__global__ __launch_bounds__(1024) void hist_kernel(const int* __restrict__ src,
                                                    const int* __restrict__ dst,
                                                    unsigned int* __restrict__ hist_dst,
                                                    unsigned int* __restrict__ hist_src,
                                                    unsigned int* __restrict__ gA,
                                                    unsigned int* __restrict__ gB) {
    __shared__ unsigned int h[NN4];
    int b = blockIdx.x;
    if (b == 0 && threadIdx.x < 32) gA[NN * 32 + threadIdx.x] = 0u;   // phantom row
    if (b == 1 && threadIdx.x < 32) gB[NN * 32 + threadIdx.x] = 0u;
    const int* arr = (b < G) ? dst : src;
    unsigned int* outp = (b < G) ? hist_dst : hist_src;
    int bb = (b < G) ? b : b - G;
    for (int i = threadIdx.x; i < NN4; i += 1024) h[i] = 0u;
    __syncthreads();
    int base = bb * SL;
    for (int i = threadIdx.x; i < SL; i += 1024) {
        int d = arr[base + i];
        atomicAdd(&h[d >> 2], 1u << ((d & 3) * 8));   // per-slice count << 256 (random data)
    }
    __syncthreads();
    unsigned int* out32 = outp + (size_t)bb * NN4;
    for (int i = threadIdx.x; i < NN4; i += 1024) out32[i] = h[i];
}

// merge (u8 packed, 4 nodes/thread): dst -> in-place exclusive per-slice
// offsets + real count + padded(x8) partials; src -> degree sum -> dinv.
__global__ __launch_bounds__(256) void merge_kernel(unsigned int* __restrict__ hist_dst,
                                                    const unsigned int* __restrict__ hist_src,
                                                    int* __restrict__ cnt,
                                                    float* __restrict__ dinv,
                                                    int* __restrict__ partial) {
    __shared__ int s[256];
    int tid = threadIdx.x;
    int t = blockIdx.x * 256 + tid;     // packed index over NN4
    int run0 = 0, run1 = 0, run2 = 0, run3 = 0;
    if (t < NN4) {
        for (int b = 0; b < G; ++b) {
            size_t idx = (size_t)b * NN4 + t;
            unsigned int u = hist_dst[idx];
            hist_dst[idx] = (unsigned int)run0 | ((unsigned int)run1 << 8) |
                            ((unsigned int)run2 << 16) | ((unsigned int)run3 << 24);
            run0 += u & 255u; run1 += (u >> 8) & 255u;
            run2 += (u >> 16) & 255u; run3 += u >> 24;
        }
        *(int4*)&cnt[4 * t] = make_int4(run0, run1, run2, run3);
        // src degree: sum u8 lanes over G slices
        int d0 = 0, d1 = 0, d2 = 0, d3 = 0;
        for (int b = 0; b < G; ++b) {
            unsigned int u = hist_src[(size_t)b * NN4 + t];
            d0 += u & 255u; d1 += (u >> 8) & 255u;
            d2 += (u >> 16) & 255u; d3 += u >> 24;
        }
        float e0 = (float)(d0 < 1 ? 1 : d0);
        float e1 = (float)(d1 < 1 ? 1 : d1);
        float e2 = (float)(d2 < 1 ? 1 : d2);
        float e3 = (float)(d3 < 1 ? 1 : d3);
        *(float4*)&dinv[4 * t] = make_float4(1.0f / sqrtf(e0), 1.0f / sqrtf(e1),
                                             1.0f / sqrtf(e2), 1.0f / sqrtf(e3));
    }
    int pad = ((run0 + 7) & ~7) + ((run1 + 7) & ~7) + ((run2 + 7) & ~7) + ((run3 + 7) & ~7);
    s[tid] = pad;
    __syncthreads();
    for (int off = 128; off > 0; off >>= 1) {
        if (tid < off) s[tid] += s[tid + off];
        __syncthreads();
    }
    if (tid == 0) partial[blockIdx.x] = s[0];
}

__global__ __launch_bounds__(256) void scan_partials_kernel(const int* __restrict__ partial,
                                                            int* __restrict__ offsets,
                                                            int* __restrict__ row_ptr) {
    __shared__ int s[256];
    int tid = threadIdx.x;
    s[tid] = (tid < NB4) ? partial[tid] : 0;
    __syncthreads();
    for (int off = 1; off < 256; off <<= 1) {
        int t = (tid >= off) ? s[tid - off] : 0;
        __syncthreads();
        s[tid] += t;
        __syncthreads();
    }
    if (tid < NB4) offsets[tid] = (tid == 0) ? 0 : s[tid - 1];
    if (tid == NB4 - 1) row_ptr[NN] = s[tid];     // total PADDED edges
}

// row_ptr (padded x8, every row start % 8 == 0) + phantom padding into col.
// col entries hold (node << 5) so prop's gather offset is colv + c2.
__global__ __launch_bounds__(256) void scan_write_kernel(const int* __restrict__ cnt,
                                                         const int* __restrict__ offsets,
                                                         int* __restrict__ row_ptr,
                                                         int* __restrict__ col) {
    __shared__ int s[256];
    int tid = threadIdx.x;
    int t = blockIdx.x * 256 + tid;
    int4 c = make_int4(0, 0, 0, 0);
    if (t < NN4) c = *(const int4*)&cnt[4 * t];
    int p0 = (c.x + 7) & ~7, p1 = (c.y + 7) & ~7, p2 = (c.z + 7) & ~7, p3 = (c.w + 7) & ~7;
    int csum = p0 + p1 + p2 + p3;
    s[tid] = csum;
    __syncthreads();
    for (int off = 1; off < 256; off <<= 1) {
        int v = (tid >= off) ? s[tid - off] : 0;
        __syncthreads();
        s[tid] += v;
        __syncthreads();
    }
    if (t < NN4) {
        int b0 = offsets[blockIdx.x] + s[tid] - csum;
        int b1 = b0 + p0, b2 = b1 + p1, b3 = b2 + p2;
        *(int4*)&row_ptr[4 * t] = make_int4(b0, b1, b2, b3);
        const int PH = NN << 5;                            // phantom (zero row)
        for (int k = c.x; k < p0; ++k) col[b0 + k] = PH;
        for (int k = c.y; k < p1; ++k) col[b1 + k] = PH;
        for (int k = c.z; k < p2; ++k) col[b2 + k] = PH;
        for (int k = c.w; k < p3; ++k) col[b3 + k] = PH;
    }
}

// ---- fill: deterministic placement, LDS-rank only, no global atomics -------
__global__ __launch_bounds__(1024) void fill_kernel(const int* __restrict__ src,
                                                    const int* __restrict__ dst,
                                                    const unsigned char* __restrict__ hist8,
                                                    const int* __restrict__ row_ptr,
                                                    int* __restrict__ col) {
    __shared__ unsigned int cur[NN4];
    int b = blockIdx.x;
    for (int i = threadIdx.x; i < NN4; i += 1024) cur[i] = 0u;
    __syncthreads();
    int base = b * SL;
    const unsigned char* hrow = hist8 + (size_t)b * NN;
    for (int i = threadIdx.x; i < SL; i += 1024) {
        int d = dst[base + i];
        int sh = (d & 3) * 8;
        unsigned int old = atomicAdd(&cur[d >> 2], 1u << sh);
        int rank = (int)((old >> sh) & 255u);
        int pos = row_ptr[d] + (int)hrow[d] + rank;
        col[pos] = src[base + i] << 5;                     // pre-scaled for gather
    }
}

// ---- W prep: Wt[n][k] = fp16(W[k][n]), 64 x 256 ----------------------------
__global__ __launch_bounds__(256) void wprep_kernel(const float* __restrict__ W,
                                                    unsigned short* __restrict__ Wt) {
    int id = blockIdx.x * 256 + threadIdx.x;   // over 64*256
    if (id >= HF * INF) return;
    int n = id >> 8;       // 0..63
    int k = id & 255;      // 0..255
    Wt[id] = f2h(W[k * HF + n]);
}

// ---- MFMA fp16 GEMM: h = leaky_relu(x @ W + b); f fp32; g fp16(h*dinv) -----
__global__ __launch_bounds__(256) void gemm_kernel(const float* __restrict__ x,
                                                   const unsigned short* __restrict__ Wt,
                                                   const float* __restrict__ b,
                                                   const float* __restrict__ dinv,
                                                   float* __restrict__ f,
                                                   unsigned short* __restrict__ g) {
    __shared__ _Float16 wls[64 * 264];   // row stride 264: banks +4/row
    __shared__ _Float16 xls[64 * 136];   // row stride 136: banks +4/row
    int tid = threadIdx.x;
    int row0 = blockIdx.x * 64;
    int wave = tid >> 6;
    int lane = tid & 63;
    int q = lane >> 4;        // quad 0..3
    int ln = lane & 15;

    // stage Wt: 64 rows x 32 x 16B chunks = 2048 chunks
    {
        const uint4* wg = (const uint4*)Wt;
        for (int i = 0; i < 8; ++i) {
            int l = tid + i * 256;
            int r = l >> 5, c = l & 31;
            *(uint4*)&wls[r * 264 + c * 8] = wg[l];
        }
    }

    floatx4 acc[4] = {{0.f,0.f,0.f,0.f},{0.f,0.f,0.f,0.f},{0.f,0.f,0.f,0.f},{0.f,0.f,0.f,0.f}};

    for (int ch = 0; ch < 2; ++ch) {
        __syncthreads();   // protect xls reuse (and Wt on first pass)
        for (int i = 0; i < 8; ++i) {
            int l = tid + i * 256;
            int r = l >> 5, c4 = (l & 31) * 4;
            int grow = row0 + r;
            f32x4 v = {0.f, 0.f, 0.f, 0.f};
            if (grow < NN) v = __builtin_nontemporal_load((const f32x4*)&x[(size_t)grow * INF + ch * 128 + c4]);
            ushort4 hv;
            hv.x = f2h(v[0]); hv.y = f2h(v[1]); hv.z = f2h(v[2]); hv.w = f2h(v[3]);
            *(ushort4*)&xls[r * 136 + c4] = hv;
        }
        __syncthreads();
        int m = wave * 16 + ln;
        #pragma unroll
        for (int kb4 = 0; kb4 < 4; ++kb4) {
            int kb = kb4 * 32;
            half8 a = *(const half8*)&xls[m * 136 + kb + q * 8];
            int kg = ch * 128 + kb + q * 8;
            #pragma unroll
            for (int t = 0; t < 4; ++t) {
                half8 bb = *(const half8*)&wls[(t * 16 + ln) * 264 + kg];
                acc[t] = __builtin_amdgcn_mfma_f32_16x16x32_f16(a, bb, acc[t], 0, 0, 0);
            }
        }
    }

    // epilogue: lane holds rows wave*16 + q*4 + r, col t*16 + ln
    float bias[4];
    #pragma unroll
    for (int t = 0; t < 4; ++t) bias[t] = b[t * 16 + ln];
    #pragma unroll
    for (int r = 0; r < 4; ++r) {
        int grow = row0 + wave * 16 + q * 4 + r;
        if (grow < NN) {
            float dv = dinv[grow];
            #pragma unroll
            for (int t = 0; t < 4; ++t) {
                float h = acc[t][r] + bias[t];
                h = (h > 0.f) ? h : 0.01f * h;
                int cidx = t * 16 + ln;
                f[(size_t)grow * HF + cidx] = h;
                g[(size_t)grow * HF + cidx] = f2h(h * dv);
            }
        }
    }
}

// 8-edge gather+accumulate (col values pre-scaled by 32; phantom row is zero)
#define ACC8(ca, cb)                                                           \
    do {                                                                       \
        unsigned int u0 = g_in[(unsigned)(ca.x + c2)];                         \
        unsigned int u1 = g_in[(unsigned)(ca.y + c2)];                         \
        unsigned int u2 = g_in[(unsigned)(ca.z + c2)];                         \
        unsigned int u3 = g_in[(unsigned)(ca.w + c2)];                         \
        unsigned int u4 = g_in[(unsigned)(cb.x + c2)];                         \
        unsigned int u5 = g_in[(unsigned)(cb.y + c2)];                         \
        unsigned int u6 = g_in[(unsigned)(cb.z + c2)];                         \
        unsigned int u7 = g_in[(unsigned)(cb.w + c2)];                         \
        s0 += ((h2f(u0 & 0xFFFF) + h2f(u1 & 0xFFFF)) + (h2f(u2 & 0xFFFF) + h2f(u3 & 0xFFFF)))  \
            + ((h2f(u4 & 0xFFFF) + h2f(u5 & 0xFFFF)) + (h2f(u6 & 0xFFFF) + h2f(u7 & 0xFFFF))); \
        s1 += ((h2f(u0 >> 16) + h2f(u1 >> 16)) + (h2f(u2 >> 16) + h2f(u3 >> 16)))              \
            + ((h2f(u4 >> 16) + h2f(u5 >> 16)) + (h2f(u6 >> 16) + h2f(u7 >> 16)));             \
    } while (0)

// prop: 32 lanes per node (2 nodes/wave), lane handles feature pair 2c,2c+1.
// rows padded to x8 -> pure 8-edge loop, software-pipelined col loads.
__global__ __launch_bounds__(256) void prop_kernel(const int* __restrict__ row_ptr,
                                                   const int* __restrict__ col,
                                                   const float* __restrict__ dinv,
                                                   const unsigned int* __restrict__ g_in,
                                                   const float* __restrict__ f_in, int fin_stride,
                                                   float* __restrict__ f_out, int fout_stride,
                                                   unsigned int* __restrict__ g_out) {
    int gidx = blockIdx.x * 256 + threadIdx.x;
    int wid = gidx >> 5;              // node
    int c2 = threadIdx.x & 31;        // feature pair
    if (wid >= NN) return;
    int j   = row_ptr[wid];
    int end = row_ptr[wid + 1];
    float dv = dinv[wid];
    f32x2 fv = __builtin_nontemporal_load((const f32x2*)&f_in[(size_t)wid * fin_stride + 2 * c2]);
    float s0 = 0.f, s1 = 0.f;
    if (j < end) {
        const int4* c4p = (const int4*)(col + j);
        int nit = (end - j) >> 3;
        int4 ca = c4p[0], cb = c4p[1];
        c4p += 2;
        for (int it = 1; it < nit; ++it) {
            int4 na = c4p[0], nb = c4p[1];   // prefetch next 8 cols
            c4p += 2;
            ACC8(ca, cb);
            ca = na; cb = nb;
        }
        ACC8(ca, cb);
    }
    float fx = fv[0] - s0 * dv;
    float fy = fv[1] - s1 * dv;
    f32x2 ov; ov[0] = fx; ov[1] = fy;
    __builtin_nontemporal_store(ov, (f32x2*)&f_out[(size_t)wid * fout_stride + 2 * c2]);
    if (g_out) g_out[wid * 32 + c2] = (unsigned int)f2h(fx * dv) | ((unsigned int)f2h(fy * dv) << 16);
}

// last prop (k=6) fused with the theta combination: reads f5 (slot3) + the
// earlier f2..f4 slots, computes f6, writes all 5 combined output slots.
__global__ __launch_bounds__(256) void prop_final_kernel(const int* __restrict__ row_ptr,
                                                         const int* __restrict__ col,
                                                         const float* __restrict__ dinv,
                                                         const unsigned int* __restrict__ g_in,
                                                         float* __restrict__ out, ThetaM tm) {
    int gidx = blockIdx.x * 256 + threadIdx.x;
    int wid = gidx >> 5;              // node
    int c2 = threadIdx.x & 31;        // feature pair
    if (wid >= NN) return;
    int j   = row_ptr[wid];
    int end = row_ptr[wid + 1];
    float dv = dinv[wid];
    float* orow = out + (size_t)wid * OUTF + 2 * c2;
    f32x2 v2 = *(const f32x2*)&orow[0 * HF];     // f2
    f32x2 v3 = *(const f32x2*)&orow[1 * HF];     // f3
    f32x2 v4 = *(const f32x2*)&orow[2 * HF];     // f4
    f32x2 v5 = *(const f32x2*)&orow[3 * HF];     // f5
    float s0 = 0.f, s1 = 0.f;
    if (j < end) {
        const int4* c4p = (const int4*)(col + j);
        int nit = (end - j) >> 3;
        int4 ca = c4p[0], cb = c4p[1];
        c4p += 2;
        for (int it = 1; it < nit; ++it) {
            int4 na = c4p[0], nb = c4p[1];
            c4p += 2;
            ACC8(ca, cb);
            ca = na; cb = nb;
        }
        ACC8(ca, cb);
    }
    f32x2 v6; v6[0] = v5[0] - s0 * dv; v6[1] = v5[1] - s1 * dv;
    f32x2 v[5] = {v2, v3, v4, v5, v6};
    #pragma unroll
    for (int t = 0; t < 5; ++t) {
        f32x2 o = {0.f, 0.f};
        #pragma unroll
        for (int jj = 0; jj < 5; ++jj) {
            if (jj >= t) { o[0] += tm.m[t][jj + 2] * v[jj][0]; o[1] += tm.m[t][jj + 2] * v[jj][1]; }
        }
        __builtin_nontemporal_store(o, (f32x2*)&orow[t * HF]);
    }
}

// ---------------- launch -----------------------------------------------------
extern "C" void kernel_launch(void* const* d_in, const int* in_sizes, int n_in,
                              void* d_out, int out_size, void* d_ws, size_t ws_size,
                              hipStream_t stream) {
    const float* x  = (const float*)d_in[0];
    const float* W  = (const float*)d_in[1];
    const float* b  = (const float*)d_in[2];
    const int* src  = (const int*)d_in[3];
    const int* dst  = (const int*)d_in[4];
    float* out = (float*)d_out;

    char* ws = (char*)d_ws;
    size_t off = 0;
    auto alloc = [&](size_t bytes) -> void* {
        void* p = ws + off;
        off += (bytes + 255) & ~(size_t)255;
        return p;
    };
    unsigned int* hist_dst = (unsigned int*)alloc((size_t)G * NN4 * 4);   // 6.4MB u8-packed
    unsigned int* hist_src = (unsigned int*)alloc((size_t)G * NN4 * 4);   // 6.4MB u8-packed
    int*   cnt     = (int*)alloc((size_t)NN * 4);
    int*   row_ptr = (int*)alloc((size_t)(NN + 1) * 4);
    int*   partial = (int*)alloc((size_t)NB4 * 4);
    int*   offsets = (int*)alloc((size_t)NB4 * 4);
    float* dinv    = (float*)alloc((size_t)NN * 4);
    int*   col     = (int*)alloc((size_t)(NE + 8 * NN) * 4);              // padded(x8) CSR
    unsigned short* wt = (unsigned short*)alloc((size_t)HF * INF * 2);
    float* fbuf    = (float*)alloc((size_t)NN * HF * 4);
    unsigned short* gA = (unsigned short*)alloc((size_t)(NN + 1) * HF * 2);  // +phantom row
    unsigned short* gB = (unsigned short*)alloc((size_t)(NN + 1) * HF * 2);

    hist_kernel<<<2 * G, 1024, 0, stream>>>(src, dst, hist_dst, hist_src,
                                            (unsigned int*)gA, (unsigned int*)gB);
    merge_kernel<<<NB4, 256, 0, stream>>>(hist_dst, hist_src, cnt, dinv, partial);
    scan_partials_kernel<<<1, 256, 0, stream>>>(partial, offsets, row_ptr);
    scan_write_kernel<<<NB4, 256, 0, stream>>>(cnt, offsets, row_ptr, col);
    fill_kernel<<<G, 1024, 0, stream>>>(src, dst, (const unsigned char*)hist_dst, row_ptr, col);
    wprep_kernel<<<(HF * INF + 255) / 256, 256, 0, stream>>>(W, wt);
    gemm_kernel<<<(NN + 63) / 64, 256, 0, stream>>>(x, wt, b, dinv, fbuf, gA);

    ThetaM tm;
    compute_theta(tm);

    const int PB = (NN * 32 + 255) / 256;
    // k=1: f stays in fbuf; g: gA -> gB
    prop_kernel<<<PB, 256, 0, stream>>>(row_ptr, col, dinv, (unsigned int*)gA, fbuf, HF, fbuf, HF, (unsigned int*)gB);
    // k=2: f: fbuf -> slot0; g: gB -> gA
    prop_kernel<<<PB, 256, 0, stream>>>(row_ptr, col, dinv, (unsigned int*)gB, fbuf, HF, out + 0 * HF, OUTF, (unsigned int*)gA);
    // k=3: slot0 -> slot1; g: gA -> gB
    prop_kernel<<<PB, 256, 0, stream>>>(row_ptr, col, dinv, (unsigned int*)gA, out + 0 * HF, OUTF, out + 1 * HF, OUTF, (unsigned int*)gB);
    // k=4: slot1 -> slot2; g: gB -> gA
    prop_kernel<<<PB, 256, 0, stream>>>(row_ptr, col, dinv, (unsigned int*)gB, out + 1 * HF, OUTF, out + 2 * HF, OUTF, (unsigned int*)gA);
    // k=5: slot2 -> slot3; g: gA -> gB
    prop_kernel<<<PB, 256, 0, stream>>>(row_ptr, col, dinv, (unsigned int*)gA, out + 2 * HF, OUTF, out + 3 * HF, OUTF, (unsigned int*)gB);
    // k=6 fused with theta combination: reads slots0-3 + gather(gB), writes slots0-4
    prop_final_kernel<<<PB, 256, 0, stream>>>(row_ptr, col, dinv, (unsigned int*)gB, out, tm);
}